// Round 10
// baseline (1611.703 us; speedup 1.0000x reference)
//
#include <hip/hip_runtime.h>
#include <cstdint>
#include <cstddef>

#define SEQ 512
#define BATCH 256
#define SD 1024
#define OD 256
#define NG 16          // groups (batch tiles)
#define GB 16          // batches per group
#define NW 16          // workgroups per group

typedef short  bf8   __attribute__((ext_vector_type(8)));
typedef float  f32x4 __attribute__((ext_vector_type(4)));
typedef unsigned int u32x4 __attribute__((ext_vector_type(4)));

union BF16x8 { unsigned long long q[2]; u32x4 u; bf8 v; };

template <bool V> struct BoolC { static constexpr bool value = V; };

__device__ __forceinline__ unsigned short f2bf(float f) {
    unsigned u = __float_as_uint(f);
    u += 0x7FFFu + ((u >> 16) & 1u);      // round-to-nearest-even
    return (unsigned short)(u >> 16);
}

__device__ __forceinline__ float fast_tanh(float v) {
    float e = __expf(2.0f * v);
    return 1.0f - 2.0f / (e + 1.0f);
}

// agent-scope access: coherence point beyond L2, correct for ANY placement.
__device__ __forceinline__ bf8 t_load16_agent(const unsigned short* p) {
    BF16x8 u;
    unsigned long long* q = (unsigned long long*)p;
    u.q[0] = __hip_atomic_load(q,     __ATOMIC_RELAXED, __HIP_MEMORY_SCOPE_AGENT);
    u.q[1] = __hip_atomic_load(q + 1, __ATOMIC_RELAXED, __HIP_MEMORY_SCOPE_AGENT);
    return u.v;
}

// HW-verified facts driving this design:
//  (r6) 16 same-XCD WGs (checked via HW_REG_XCC_ID): t data path L2-local --
//       plain stores (write-through L1 -> XCD L2) + sc0 loads. FETCH 219->89MB.
//  (r7) sc0/plain LOAD polling of a hot line serves stale L1 data. BUT
//       workgroup-scope global_atomic_add RMWs execute correctly at the
//       local XCD L2 (r7's phase counters were all correct).
//  (r8) per-WG agent flags (store + load poll) work: 1455->1277us.
//  (r9) assembler: modifier order is `off offset:N sc0` (cache flag LAST).
//
// Round-10 barrier (FAST groups): flags live in the XCD L2.
//  publish: drain (syncthreads) + workgroup-scope fetch_add(+1) (L2 RMW,
//           r7-validated) + agent mirror store (fallback only).
//  wait:    16 returning global_atomic_add(0) in ONE asm burst (atomics
//           always execute at L2 -- immune to the r7 L1-staleness trap;
//           inline asm because LLVM folds idempotent atomicrmw into an
//           atomic LOAD, which would reintroduce r7). s_sleep throttle;
//           after 1024 rounds fall back to agent mirrors -> cannot hang.
// Flags spread one per 64B line (atomic same-line serialization).
// Slow path (placement check fails): byte-identical r8 agent-scope scheme.
__global__ void __launch_bounds__(256, 1)
rnn_persistent(const float* __restrict__ x,
               const float* __restrict__ h_init,
               const float* __restrict__ w_r,
               const float* __restrict__ b_r,
               const float* __restrict__ w_o,
               const float* __restrict__ b_o,
               float* __restrict__ out,
               unsigned char* __restrict__ ws)
{
    const int wg   = blockIdx.x;
    const int g    = wg & 15;      // group; members share blockIdx mod 8 -> same XCD (verified below)
    const int wi   = wg >> 4;      // 0..15 within group
    const int tid  = threadIdx.x;
    const int lane = tid & 63;
    const int wid  = tid >> 6;     // wave 0..3
    const int l15  = lane & 15;
    const int lq   = lane >> 4;    // k-quad 0..3

    // ws layout:
    //  [0, 16K)   flags: group g -> 16 flags at ws + g*1024 + wi*64 (one line each)
    //  [16K, 20K) startup blocks, 256B/group: +0 scnt | +4 sflag | +8 xarr[16] | +128 mirror[16]
    //  [32K, ...) t triple buffer: 3 x [256][1024] bf16
    unsigned* gflags = (unsigned*)(ws + (size_t)g * 1024);
    unsigned* const myflag = (unsigned*)(ws + (size_t)g * 1024 + (size_t)wi * 64);
    unsigned char* gctl = ws + 16384 + (size_t)g * 256;
    unsigned* scnt   = (unsigned*)(gctl + 0);
    unsigned* sflag  = (unsigned*)(gctl + 4);
    unsigned* xarr   = (unsigned*)(gctl + 8);
    unsigned* mirror = (unsigned*)(gctl + 128);
    unsigned short* tbase = (unsigned short*)(ws + 32768);

    const int batch0 = g * GB;     // group's batch rows
    const int s0 = wi * 64;        // wg's state cols
    const int o0 = wi * 16;        // wg's output cols
    const int k0 = wid * 256;      // wave's K slice

    __shared__ float red1[4][4][4][68];  // [wave][coltile][reg][lane] (+4 pad: bank spread)
    __shared__ float red2[4][4][68];     // [wave][reg][lane]
    __shared__ unsigned sx[16];

    // ---- preload w_r slice as B fragments in registers (128 VGPRs) ----
    bf8 B1[4][8];
#pragma unroll
    for (int ct = 0; ct < 4; ++ct) {
#pragma unroll
        for (int kk = 0; kk < 8; ++kk) {
            const float* p = w_r + (size_t)(s0 + ct * 16 + l15) * SD + (k0 + kk * 32 + lq * 8);
            bf8 f;
#pragma unroll
            for (int j = 0; j < 8; ++j) f[j] = (short)f2bf(p[j]);
            B1[ct][kk] = f;
        }
    }
    // ---- w_o slice: 16 rows -> full N=16 tile ----
    bf8 B2[8];
#pragma unroll
    for (int kk = 0; kk < 8; ++kk) {
        const float* p = w_o + (size_t)(o0 + l15) * SD + (k0 + kk * 32 + lq * 8);
        bf8 f;
#pragma unroll
        for (int j = 0; j < 8; ++j) f[j] = (short)f2bf(p[j]);
        B2[kk] = f;
    }

    // ---- per-thread h ownership: 4 consecutive states of one batch row ----
    const int hr = tid >> 4;            // batch-local row 0..15
    const int hc = (tid & 15) * 4;      // state-local col base 0..60
    float4 br4  = *(const float4*)(b_r + s0 + hc);
    float4 hreg = *(const float4*)(h_init + (size_t)(batch0 + hr) * SD + s0 + hc);

    const int ct1 = hc >> 4;
    const int rg1 = hr & 3;
    const int ln1 = (hr >> 2) * 16 + (hc & 15);

    const int er  = tid >> 4;           // err element (row, col): one per thread
    const int ec  = tid & 15;
    const int rg2 = er & 3;
    const int ln2 = (er >> 2) * 16 + ec;
    const float bo = b_o[o0 + ec];

    const size_t t_off = (size_t)(batch0 + hr) * SD + s0 + hc;

    // ---- one-time XCD placement check (agent-scope, always correct) ----
    unsigned xcc = 0;
    asm volatile("s_getreg_b32 %0, hwreg(HW_REG_XCC_ID)" : "=s"(xcc));
    if (tid == 0)
        __hip_atomic_store(xarr + wi, xcc + 1u, __ATOMIC_RELAXED, __HIP_MEMORY_SCOPE_AGENT);
    __syncthreads();   // drains the xcc store (vmcnt) before the arrival add
    if (tid == 0) {
        unsigned old = __hip_atomic_fetch_add(scnt, 1u, __ATOMIC_RELAXED, __HIP_MEMORY_SCOPE_AGENT);
        if (old == 15u)
            __hip_atomic_store(sflag, 1u, __ATOMIC_RELAXED, __HIP_MEMORY_SCOPE_AGENT);
        while (__hip_atomic_load(sflag, __ATOMIC_RELAXED, __HIP_MEMORY_SCOPE_AGENT) < 1u)
            __builtin_amdgcn_s_sleep(1);
    }
    __syncthreads();
    if (tid < 16)
        sx[tid] = __hip_atomic_load(xarr + tid, __ATOMIC_RELAXED, __HIP_MEMORY_SCOPE_AGENT);
    __syncthreads();
    bool fastpath = true;
    for (int j = 1; j < 16; ++j) fastpath &= (sx[j] == sx[0]);

    // ================= main body, specialized on FAST =================
    auto body = [&](auto FC) {
        constexpr bool FAST = decltype(FC)::value;

        auto t_store = [&](unsigned short* p, float a, float b, float c, float d) {
            unsigned long long v = (unsigned long long)f2bf(a)
                                 | ((unsigned long long)f2bf(b) << 16)
                                 | ((unsigned long long)f2bf(c) << 32)
                                 | ((unsigned long long)f2bf(d) << 48);
            if constexpr (FAST) {             // write-through L1 -> lands in XCD L2 (r6-verified)
                *(unsigned long long*)p = v;
            } else {
                __hip_atomic_store((unsigned long long*)p, v, __ATOMIC_RELAXED, __HIP_MEMORY_SCOPE_AGENT);
            }
        };

        // load 8 A fragments; FAST: sc0 loads serve from XCD L2 (r6-verified)
        auto loadA = [&](bf8 (&A)[8], const unsigned short* ap) {
            if constexpr (FAST) {
                u32x4 r[8];
#pragma unroll
                for (int kk = 0; kk < 8; ++kk)
                    asm volatile("global_load_dwordx4 %0, %1, off sc0"
                                 : "=v"(r[kk]) : "v"((const void*)(ap + kk * 32)));
                asm volatile("s_waitcnt vmcnt(0)" ::: "memory");
                __builtin_amdgcn_sched_barrier(0);   // rule #18: keep MFMAs after the wait
#pragma unroll
                for (int kk = 0; kk < 8; ++kk) {
                    BF16x8 u; u.u = r[kk]; A[kk] = u.v;
                }
            } else {
#pragma unroll
                for (int kk = 0; kk < 8; ++kk) A[kk] = t_load16_agent(ap + kk * 32);
            }
        };

        // ---- publish: drain + flag (L2 RMW fast / agent store slow) ----
        auto publish = [&](unsigned val) {
            __syncthreads();  // drains vmcnt: all t-stores at L2 (FAST) / coherence pt (slow)
            if (tid == 0) {
                if constexpr (FAST) {
                    // L2-local RMW (r7-validated primitive); +1 per phase == val
                    __hip_atomic_fetch_add(myflag, 1u, __ATOMIC_RELAXED, __HIP_MEMORY_SCOPE_WORKGROUP);
                    // hang-proof mirror at agent scope (fallback detection only)
                    __hip_atomic_store(mirror + wi, val, __ATOMIC_RELAXED, __HIP_MEMORY_SCOPE_AGENT);
                } else {
                    __hip_atomic_store(myflag, val, __ATOMIC_RELAXED, __HIP_MEMORY_SCOPE_AGENT);
                }
            }
        };

        // ---- wait: L2 atomic-RMW poll (fast) / agent load poll (slow) ----
        auto wait_all = [&](unsigned target) {
            if (tid == 0) {
                if constexpr (FAST) {
                    unsigned long long fa = (unsigned long long)(uintptr_t)gflags;
                    int rounds = 0;
                    for (;;) {
                        unsigned v0,v1,v2,v3,v4,v5,v6,v7,v8,v9,v10,v11,v12,v13,v14,v15;
                        // 16 returning atomic adds of 0: execute at the XCD L2
                        // (atomics never satisfied from L1 -> no r7 staleness).
                        // NOTE r9: modifier order is `offset:N sc0` -- flag last.
                        asm volatile(
                            "global_atomic_add %0, %16, %17, off sc0\n\t"
                            "global_atomic_add %1, %16, %17, off offset:64 sc0\n\t"
                            "global_atomic_add %2, %16, %17, off offset:128 sc0\n\t"
                            "global_atomic_add %3, %16, %17, off offset:192 sc0\n\t"
                            "global_atomic_add %4, %16, %17, off offset:256 sc0\n\t"
                            "global_atomic_add %5, %16, %17, off offset:320 sc0\n\t"
                            "global_atomic_add %6, %16, %17, off offset:384 sc0\n\t"
                            "global_atomic_add %7, %16, %17, off offset:448 sc0\n\t"
                            "global_atomic_add %8, %16, %17, off offset:512 sc0\n\t"
                            "global_atomic_add %9, %16, %17, off offset:576 sc0\n\t"
                            "global_atomic_add %10, %16, %17, off offset:640 sc0\n\t"
                            "global_atomic_add %11, %16, %17, off offset:704 sc0\n\t"
                            "global_atomic_add %12, %16, %17, off offset:768 sc0\n\t"
                            "global_atomic_add %13, %16, %17, off offset:832 sc0\n\t"
                            "global_atomic_add %14, %16, %17, off offset:896 sc0\n\t"
                            "global_atomic_add %15, %16, %17, off offset:960 sc0\n\t"
                            "s_waitcnt vmcnt(0)"
                            : "=&v"(v0), "=&v"(v1), "=&v"(v2), "=&v"(v3),
                              "=&v"(v4), "=&v"(v5), "=&v"(v6), "=&v"(v7),
                              "=&v"(v8), "=&v"(v9), "=&v"(v10), "=&v"(v11),
                              "=&v"(v12), "=&v"(v13), "=&v"(v14), "=&v"(v15)
                            : "v"(fa), "v"(0u)
                            : "memory");
                        unsigned mn = v0;
                        mn = v1  < mn ? v1  : mn;  mn = v2  < mn ? v2  : mn;
                        mn = v3  < mn ? v3  : mn;  mn = v4  < mn ? v4  : mn;
                        mn = v5  < mn ? v5  : mn;  mn = v6  < mn ? v6  : mn;
                        mn = v7  < mn ? v7  : mn;  mn = v8  < mn ? v8  : mn;
                        mn = v9  < mn ? v9  : mn;  mn = v10 < mn ? v10 : mn;
                        mn = v11 < mn ? v11 : mn;  mn = v12 < mn ? v12 : mn;
                        mn = v13 < mn ? v13 : mn;  mn = v14 < mn ? v14 : mn;
                        mn = v15 < mn ? v15 : mn;
                        if (mn >= target) break;
                        if (++rounds > 1024) {   // safety net: agent mirrors (r7-proven detect)
                            unsigned m2 = 0xFFFFFFFFu;
#pragma unroll
                            for (int j = 0; j < 16; ++j) {
                                unsigned v = __hip_atomic_load(mirror + j, __ATOMIC_RELAXED, __HIP_MEMORY_SCOPE_AGENT);
                                m2 = v < m2 ? v : m2;
                            }
                            if (m2 >= target) break;
                            __builtin_amdgcn_s_sleep(1);
                            rounds = 1024;
                        }
                        __builtin_amdgcn_s_sleep(1);
                    }
                } else {
                    for (;;) {
                        unsigned mn = 0xFFFFFFFFu;
#pragma unroll
                        for (int j = 0; j < 16; ++j) {
                            unsigned v = __hip_atomic_load((unsigned*)(ws + (size_t)g * 1024 + (size_t)j * 64),
                                                           __ATOMIC_RELAXED, __HIP_MEMORY_SCOPE_AGENT);
                            mn = v < mn ? v : mn;
                        }
                        if (mn >= target) break;
                        __builtin_amdgcn_s_sleep(1);
                    }
                }
            }
            __syncthreads();
        };

        bf8 A[8];  // A fragments of current t tile (reused by gemm1 AND gemm2)
        size_t g2_oidx = 0;
        float  g2_xv   = 0.f;

        // gemm2 split: front (x prefetch + MFMA + red2 write) overlaps the
        // barrier poll; back (4-wave reduce + out store) runs after the
        // wait's syncthreads (which orders red2 for free).
        auto gemm2_front = [&](int tstep) {
            g2_oidx = (size_t)tstep * (BATCH * OD) + (size_t)(batch0 + er) * OD + o0 + ec;
            g2_xv = x[g2_oidx];                       // issue early, overlaps MFMA+poll
            f32x4 c = {0.f, 0.f, 0.f, 0.f};
#pragma unroll
            for (int kk = 0; kk < 8; ++kk)
                c = __builtin_amdgcn_mfma_f32_16x16x32_bf16(A[kk], B2[kk], c, 0, 0, 0);
#pragma unroll
            for (int q = 0; q < 4; ++q) red2[wid][q][lane] = c[q];
        };
        auto gemm2_back = [&]() {
            float sum = red2[0][rg2][ln2] + red2[1][rg2][ln2]
                      + red2[2][rg2][ln2] + red2[3][rg2][ln2];
            out[g2_oidx] = sum + bo - g2_xv;
        };

        // ---- t0 = tanh(h_init) into buffer 0 ----
        t_store(tbase + t_off, fast_tanh(hreg.x), fast_tanh(hreg.y),
                               fast_tanh(hreg.z), fast_tanh(hreg.w));
        publish(1u);
        wait_all(1u);

        for (int i = 0; i < SEQ; ++i) {
            const unsigned short* tb = tbase + (size_t)(i % 3) * (BATCH * SD);
            unsigned short* tn = tbase + (size_t)((i + 1) % 3) * (BATCH * SD);

            // ---- A fragments: 16 rows x wave's K slice ----
            const unsigned short* ap = tb + (size_t)(batch0 + l15) * SD + k0 + lq * 8;
            loadA(A, ap);

            // ---- recurrent GEMM: C[16x64] per wave over its K slice ----
            f32x4 acc0 = {0.f,0.f,0.f,0.f}, acc1 = {0.f,0.f,0.f,0.f};
            f32x4 acc2 = {0.f,0.f,0.f,0.f}, acc3 = {0.f,0.f,0.f,0.f};
#pragma unroll
            for (int kk = 0; kk < 8; ++kk) {
                acc0 = __builtin_amdgcn_mfma_f32_16x16x32_bf16(A[kk], B1[0][kk], acc0, 0, 0, 0);
                acc1 = __builtin_amdgcn_mfma_f32_16x16x32_bf16(A[kk], B1[1][kk], acc1, 0, 0, 0);
                acc2 = __builtin_amdgcn_mfma_f32_16x16x32_bf16(A[kk], B1[2][kk], acc2, 0, 0, 0);
                acc3 = __builtin_amdgcn_mfma_f32_16x16x32_bf16(A[kk], B1[3][kk], acc3, 0, 0, 0);
            }
#pragma unroll
            for (int q = 0; q < 4; ++q) {
                red1[wid][0][q][lane] = acc0[q];
                red1[wid][1][q][lane] = acc1[q];
                red1[wid][2][q][lane] = acc2[q];
                red1[wid][3][q][lane] = acc3[q];
            }
            __syncthreads();

            // ---- K-reduction across 4 waves + leaky h update + tanh + publish ----
            float4 p0 = *(const float4*)&red1[0][ct1][rg1][ln1];
            float4 p1 = *(const float4*)&red1[1][ct1][rg1][ln1];
            float4 p2 = *(const float4*)&red1[2][ct1][rg1][ln1];
            float4 p3 = *(const float4*)&red1[3][ct1][rg1][ln1];
            hreg.x = 0.9f * hreg.x + 0.1f * (p0.x + p1.x + p2.x + p3.x + br4.x);
            hreg.y = 0.9f * hreg.y + 0.1f * (p0.y + p1.y + p2.y + p3.y + br4.y);
            hreg.z = 0.9f * hreg.z + 0.1f * (p0.z + p1.z + p2.z + p3.z + br4.z);
            hreg.w = 0.9f * hreg.w + 0.1f * (p0.w + p1.w + p2.w + p3.w + br4.w);
            t_store(tn + t_off, fast_tanh(hreg.x), fast_tanh(hreg.y),
                                fast_tanh(hreg.z), fast_tanh(hreg.w));

            publish((unsigned)(i + 2));   // drain + L2 flag RMW (+ agent mirror)

            // ---- off-critical-path: err_{i-1} front overlaps the poll ----
            if (i >= 1) gemm2_front(i - 1);

            wait_all((unsigned)(i + 2));  // t_{i+1} available from all 16 producers

            if (i >= 1) gemm2_back();     // red2 ordered by wait's syncthreads
        }

        // ---- epilogue: err_{511} from t_512 (published; last wait ordered it) ----
        {
            __syncthreads();   // separate last back-read from epilogue red2 write
            const unsigned short* tb = tbase + (size_t)(SEQ % 3) * (BATCH * SD);
            const unsigned short* ap = tb + (size_t)(batch0 + l15) * SD + k0 + lq * 8;
            loadA(A, ap);
            gemm2_front(SEQ - 1);
            __syncthreads();
            gemm2_back();
        }
    };

    if (fastpath) {
        body(BoolC<true>{});
    } else {
        body(BoolC<false>{});
    }
}

extern "C" void kernel_launch(void* const* d_in, const int* in_sizes, int n_in,
                              void* d_out, int out_size, void* d_ws, size_t ws_size,
                              hipStream_t stream)
{
    const float* x      = (const float*)d_in[0];
    const float* h_init = (const float*)d_in[1];
    const float* w_r    = (const float*)d_in[2];
    const float* b_r    = (const float*)d_in[3];
    const float* w_o    = (const float*)d_in[4];
    const float* b_o    = (const float*)d_in[5];
    float* out = (float*)d_out;

    // ws layout: [0,16K) spread flags, [16K,20K) startup+mirrors, [32K, +3*512K) t triple buffer
    hipMemsetAsync(d_ws, 0, 20480, stream);
    rnn_persistent<<<dim3(256), dim3(256), 0, stream>>>(
        x, h_init, w_r, b_r, w_o, b_o, out, (unsigned char*)d_ws);
}